// Round 1
// baseline (437.563 us; speedup 1.0000x reference)
//
#include <hip/hip_runtime.h>

// LightGCN encoder on MI355X — round 8.
// Replaced the bucketed binning + per-bucket CSR (123-block + 293-block,
// ~100 us combined, latency-exposed at <1 wave/SIMD) with a fully parallel
// global-atomic CSR build:
//   (1) lgcn_deg:     2M random atomicAdd into deg[] (977 blocks, full occ)
//   (2) lgcn_alloc:   block-scan of padded degrees + ONE atomicAdd per block
//                     reserves the segment range (segment order is
//                     irrelevant — sums are commutative); writes nodeinfo,
//                     cur, and zero-row pad slots.
//   (3) lgcn_scatter: pos = atomicAdd(&cur[dst]); packed[pos] = src.
// No 19.2 MB 'binned' intermediate, no LDS histograms, no serialized phases.
// Propagation kernels (init_g0 / pull / final) are byte-identical to round 7.
#define N_USERS 100000
#define N_NODES 150000
#define DIM 64
#define BATCH 4096
#define ALLOC_T 1024           // nodes per alloc block

typedef unsigned short bf16_t;

static __device__ __forceinline__ float bf2f(bf16_t h) {
    return __uint_as_float(((unsigned)h) << 16);
}
static __device__ __forceinline__ bf16_t f2bf(float f) {  // round-nearest-even
    unsigned u = __float_as_uint(f);
    return (bf16_t)((u + 0x7FFFu + ((u >> 16) & 1u)) >> 16);
}

// --- CSR build, phase 1: degrees ------------------------------------------
// deg[] zeroed before launch. One thread = 4 undirected pairs (int4 loads).
__global__ void lgcn_deg(const int* __restrict__ row, const int* __restrict__ col,
                         int* __restrict__ deg, int nq) {
    int q = blockIdx.x * blockDim.x + threadIdx.x;
    if (q >= nq) return;
    int4 r = ((const int4*)row)[q];
    int4 c = ((const int4*)col)[q];
    atomicAdd(&deg[r.x], 1); atomicAdd(&deg[c.x], 1);
    atomicAdd(&deg[r.y], 1); atomicAdd(&deg[c.y], 1);
    atomicAdd(&deg[r.z], 1); atomicAdd(&deg[c.z], 1);
    atomicAdd(&deg[r.w], 1); atomicAdd(&deg[c.w], 1);
}

// --- CSR build, phase 2: segment allocation --------------------------------
// Per-block exclusive scan of padded degrees; one global atomicAdd reserves
// the block's range. Segments are 16-B aligned (degp multiple of 4, block
// totals multiple of 4). Pad slots -> zero row N_NODES (disjoint from the
// scatter targets, so no ordering constraint vs lgcn_scatter).
__global__ void __launch_bounds__(ALLOC_T)
lgcn_alloc(const int* __restrict__ deg, int* __restrict__ gtot,
           int4* __restrict__ nodeinfo, int* __restrict__ cur,
           int* __restrict__ packed) {
    __shared__ int sA[ALLOC_T], sB[ALLOC_T];
    __shared__ int sBase;
    int tid = threadIdx.x;
    int n = blockIdx.x * ALLOC_T + tid;
    int d = (n < N_NODES) ? deg[n] : 0;
    int dp = (d + 3) & ~3;                 // padded segment length
    sA[tid] = dp;
    __syncthreads();
    int* c_ = sA; int* n_ = sB;
    for (int off = 1; off < ALLOC_T; off <<= 1) {
        n_[tid] = (tid >= off) ? c_[tid] + c_[tid - off] : c_[tid];
        __syncthreads();
        int* t = c_; c_ = n_; n_ = t;
    }
    if (tid == ALLOC_T - 1) sBase = atomicAdd(gtot, c_[ALLOC_T - 1]);
    __syncthreads();
    int start = sBase + c_[tid] - dp;      // exclusive scan + block base
    if (n < N_NODES) {
        float da = (d == 0) ? 1.0f : (float)d;
        float sq = sqrtf(da);
        int4 ni;
        ni.x = start;
        ni.y = d;
        ni.z = __float_as_int(1.0f / sq);
        ni.w = __float_as_int(sq);
        nodeinfo[n] = ni;
        cur[n] = start;
        for (int k = d; k < dp; ++k) packed[start + k] = N_NODES;
    }
}

// --- CSR build, phase 3: scatter -------------------------------------------
__global__ void lgcn_scatter(const int* __restrict__ row, const int* __restrict__ col,
                             int* __restrict__ cur, int* __restrict__ packed, int nq) {
    int q = blockIdx.x * blockDim.x + threadIdx.x;
    if (q >= nq) return;
    int4 r = ((const int4*)row)[q];
    int4 c = ((const int4*)col)[q];
    int rr[4] = { r.x, r.y, r.z, r.w };
    int cc[4] = { c.x, c.y, c.z, c.w };
#pragma unroll
    for (int j = 0; j < 4; ++j) {
        int p1 = atomicAdd(&cur[rr[j]], 1);
        packed[p1] = cc[j];
        int p2 = atomicAdd(&cur[cc[j]], 1);
        packed[p2] = rr[j];
    }
}

// --- Propagation -----------------------------------------------------------

// g0[n] = norm[n] * x[n]  (bf16), plus zero row N_NODES in BOTH buffers.
__global__ void lgcn_init_g0(const float* __restrict__ ue, const float* __restrict__ ie,
                             const int4* __restrict__ nodeinfo,
                             bf16_t* __restrict__ g0, bf16_t* __restrict__ g1) {
    int t = blockIdx.x * blockDim.x + threadIdx.x;     // ushort4-chunk slot
    const int nT = N_NODES * (DIM / 4);
    if (t >= nT) {
        if (t < nT + 16)
            ((ushort4*)g0)[nT + (t - nT)] = make_ushort4(0, 0, 0, 0);
        else if (t < nT + 32)
            ((ushort4*)g1)[nT + (t - nT - 16)] = make_ushort4(0, 0, 0, 0);
        return;
    }
    int n = t >> 4;
    const int nU = N_USERS * (DIM / 4);
    float4 x = (t < nU) ? ((const float4*)ue)[t] : ((const float4*)ie)[t - nU];
    float nm = __int_as_float(nodeinfo[n].z);
    ushort4 o;
    o.x = f2bf(x.x * nm); o.y = f2bf(x.y * nm);
    o.z = f2bf(x.z * nm); o.w = f2bf(x.w * nm);
    ((ushort4*)g0)[t] = o;
}

// Gather core: 16-lane group sums g rows for edges [start, start+deg).
// Pad slots point at the zero row -> plain adds, no clamps, no weights.
static __device__ __forceinline__ float4
gather_sum(const bf16_t* __restrict__ g, const int* __restrict__ packed,
           int start, int deg, int grp, int c) {
    float4 acc = make_float4(0.f, 0.f, 0.f, 0.f);
    for (int o = 4 * grp; o < deg; o += 16) {
        int4 e4 = *(const int4*)(packed + start + o);  // 16-B aligned
        ushort4 v0 = ((const ushort4*)(g + (size_t)e4.x * DIM))[c];
        ushort4 v1 = ((const ushort4*)(g + (size_t)e4.y * DIM))[c];
        ushort4 v2 = ((const ushort4*)(g + (size_t)e4.z * DIM))[c];
        ushort4 v3 = ((const ushort4*)(g + (size_t)e4.w * DIM))[c];
        acc.x += bf2f(v0.x); acc.y += bf2f(v0.y);
        acc.z += bf2f(v0.z); acc.w += bf2f(v0.w);
        acc.x += bf2f(v1.x); acc.y += bf2f(v1.y);
        acc.z += bf2f(v1.z); acc.w += bf2f(v1.w);
        acc.x += bf2f(v2.x); acc.y += bf2f(v2.y);
        acc.z += bf2f(v2.z); acc.w += bf2f(v2.w);
        acc.x += bf2f(v3.x); acc.y += bf2f(v3.y);
        acc.z += bf2f(v3.z); acc.w += bf2f(v3.w);
    }
    return acc;
}

// Full pull: gn[n] = bf16( norm[n]^2 * sum_{s in N(n)} g[s] ).
__global__ void __launch_bounds__(256)
lgcn_pull(const bf16_t* __restrict__ g, const int4* __restrict__ nodeinfo,
          const int* __restrict__ packed, bf16_t* __restrict__ gn) {
    int n = blockIdx.x * 4 + (threadIdx.x >> 6);
    if (n >= N_NODES) return;
    int lane = threadIdx.x & 63;
    int grp = lane >> 4;
    int c = lane & 15;
    int4 ni = nodeinfo[n];
    float4 acc = gather_sum(g, packed, ni.x, ni.y, grp, c);
#pragma unroll
    for (int off = 16; off < 64; off <<= 1) {
        acc.x += __shfl_xor(acc.x, off, 64);
        acc.y += __shfl_xor(acc.y, off, 64);
        acc.z += __shfl_xor(acc.z, off, 64);
        acc.w += __shfl_xor(acc.w, off, 64);
    }
    if (lane < 16) {
        float nm = __int_as_float(ni.z);
        float s2 = nm * nm;
        ushort4 o;
        o.x = f2bf(acc.x * s2); o.y = f2bf(acc.y * s2);
        o.z = f2bf(acc.z * s2); o.w = f2bf(acc.w * s2);
        ((ushort4*)(gn + (size_t)n * DIM))[c] = o;
    }
}

// Fused layer-3 + epilogue, batch nodes only:
// out[slot] = 0.25*( x[n] + rn*g1[n] + rn*g2[n] + nm*sum_{s in N(n)} g2[s] ).
__global__ void __launch_bounds__(256)
lgcn_final(const float* __restrict__ ue, const float* __restrict__ ie,
           const bf16_t* __restrict__ g1, const bf16_t* __restrict__ g2,
           const int4* __restrict__ nodeinfo, const int* __restrict__ packed,
           const int* __restrict__ uid, const int* __restrict__ iid,
           float* __restrict__ out) {
    int slot = blockIdx.x * 4 + (threadIdx.x >> 6);
    if (slot >= 2 * BATCH) return;
    int lane = threadIdx.x & 63;
    int grp = lane >> 4;
    int c = lane & 15;
    int isItem = slot >= BATCH;
    int b = isItem ? (slot - BATCH) : slot;
    int node = isItem ? (N_USERS + iid[b]) : uid[b];
    int4 ni = nodeinfo[node];
    float4 acc = gather_sum(g2, packed, ni.x, ni.y, grp, c);
#pragma unroll
    for (int off = 16; off < 64; off <<= 1) {
        acc.x += __shfl_xor(acc.x, off, 64);
        acc.y += __shfl_xor(acc.y, off, 64);
        acc.z += __shfl_xor(acc.z, off, 64);
        acc.w += __shfl_xor(acc.w, off, 64);
    }
    if (lane < 16) {
        const float* xb = isItem ? (ie + (size_t)(node - N_USERS) * DIM)
                                 : (ue + (size_t)node * DIM);
        float4 x = ((const float4*)xb)[c];
        ushort4 a1 = ((const ushort4*)(g1 + (size_t)node * DIM))[c];
        ushort4 a2 = ((const ushort4*)(g2 + (size_t)node * DIM))[c];
        float rn = __int_as_float(ni.w);
        float nm = __int_as_float(ni.z);
        float4 r;
        r.x = 0.25f * (x.x + rn * (bf2f(a1.x) + bf2f(a2.x)) + nm * acc.x);
        r.y = 0.25f * (x.y + rn * (bf2f(a1.y) + bf2f(a2.y)) + nm * acc.y);
        r.z = 0.25f * (x.z + rn * (bf2f(a1.z) + bf2f(a2.z)) + nm * acc.z);
        r.w = 0.25f * (x.w + rn * (bf2f(a1.w) + bf2f(a2.w)) + nm * acc.w);
        ((float4*)(out + (size_t)slot * DIM))[c] = r;
    }
}

// --- Launch ----------------------------------------------------------------

extern "C" void kernel_launch(void* const* d_in, const int* in_sizes, int n_in,
                              void* d_out, int out_size, void* d_ws, size_t ws_size,
                              hipStream_t stream) {
    const float* ue  = (const float*)d_in[0];
    const float* ie  = (const float*)d_in[1];
    const int*   ei  = (const int*)d_in[3];
    const int*   uid = (const int*)d_in[4];
    const int*   iid = (const int*)d_in[5];
    float* out = (float*)d_out;

    const int E  = in_sizes[2];     // 2,000,000 directed edges
    const int EH = E / 2;           // 1,000,000 undirected pairs
    const int* row = ei;            // first-half src = user ids
    const int* col = ei + E;        // first-half dst = item node ids

    // Workspace carve-up (256-B aligned), ~54 MB total.
    char* p = (char*)d_ws;
    size_t off = 0;
    auto carve = [&](size_t bytes) -> char* {
        char* r = p + off;
        off += (bytes + 255) & ~(size_t)255;
        return r;
    };
    const size_t nodeBf16 = (size_t)(N_NODES + 1) * DIM * sizeof(bf16_t); // +zero row
    bf16_t* gA       = (bf16_t*)carve(nodeBf16);
    bf16_t* gB       = (bf16_t*)carve(nodeBf16);
    int4*   nodeinfo = (int4*)carve((size_t)N_NODES * sizeof(int4));     // 2.4 MB
    int*    deg      = (int*)carve((size_t)(N_NODES + 64) * sizeof(int));
    int*    cur      = (int*)carve((size_t)N_NODES * sizeof(int));
    int*    packed   = (int*)carve((size_t)(E + 3 * N_NODES + 64) * sizeof(int)); // ~9.8 MB
    int*    gtot     = deg + N_NODES;          // zeroed with deg
    (void)ws_size;

    const int nq   = EH / 4;                   // 250,000 int4 pair-quads
    const int gEdge = (nq + 255) / 256;        // 977 blocks
    const int gAlloc = (N_NODES + ALLOC_T - 1) / ALLOC_T;  // 147 blocks

    // 1) Global-atomic CSR: degrees -> segment alloc -> scatter.
    hipMemsetAsync(deg, 0, (size_t)(N_NODES + 64) * sizeof(int), stream);
    lgcn_deg<<<gEdge, 256, 0, stream>>>(row, col, deg, nq);
    lgcn_alloc<<<gAlloc, ALLOC_T, 0, stream>>>(deg, gtot, nodeinfo, cur, packed);
    lgcn_scatter<<<gEdge, 256, 0, stream>>>(row, col, cur, packed, nq);

    // 2) g0 = norm*x (bf16) + zero rows in both buffers.
    lgcn_init_g0<<<(N_NODES * (DIM / 4) + 32 + 255) / 256, 256, 0, stream>>>(
        ue, ie, nodeinfo, gA, gB);

    // 3) Two full pulls (g1, g2), then fused batch-only layer 3 + epilogue.
    const int pullGrid = (N_NODES + 3) / 4;
    lgcn_pull<<<pullGrid, 256, 0, stream>>>(gA, nodeinfo, packed, gB);  // g1 = gB
    lgcn_pull<<<pullGrid, 256, 0, stream>>>(gB, nodeinfo, packed, gA);  // g2 = gA
    lgcn_final<<<(2 * BATCH + 3) / 4, 256, 0, stream>>>(
        ue, ie, gB, gA, nodeinfo, packed, uid, iid, out);
}

// Round 2
// 245.494 us; speedup vs baseline: 1.7824x; 1.7824x over previous
//
#include <hip/hip_runtime.h>

// LightGCN encoder on MI355X — round 9.
// Round 8 post-mortem: global per-node-cursor scatter caused 16x write
// amplification (WRITE_SIZE 128 MB = 2M x 64 B partial-line writebacks from
// 8 non-coherent XCD L2s) -> 165 us. Restored round 7's two-level bucketed
// CSR build (block-local range reservation => line-merged writes) and fixed
// its occupancy instead:
//   - lgcn_bin: PAIRS_PER_BLK 8192 -> 2048  => 489 blocks (was 123; half the
//     CUs were idle).
//   - buckets 512 -> 256 nodes (NB 586, CAP 8192) => build_csr 586x256
//     (was 293x512): 2.3 blocks/CU, finer straggler tail, shorter scan.
// Propagation kernels (init_g0 / pull / final) byte-identical to rounds 7/8.
#define N_USERS 100000
#define N_NODES 150000
#define DIM 64
#define BATCH 4096
#define BSHIFT 8
#define BUCKET 256
#define NB 586                 // ceil(150000 / 256) buckets
#define PAIRS_PER_BLK 2048     // undirected pairs per binning block
#define CAPSHIFT 13
#define CAP (1 << CAPSHIFT)    // slots per bucket region (max ~6.3K used)

typedef unsigned short bf16_t;

static __device__ __forceinline__ float bf2f(bf16_t h) {
    return __uint_as_float(((unsigned)h) << 16);
}
static __device__ __forceinline__ bf16_t f2bf(float f) {  // round-nearest-even
    unsigned u = __float_as_uint(f);
    return (bf16_t)((u + 0x7FFFu + ((u >> 16) & 1u)) >> 16);
}

// --- Fused binning: LDS hist -> range reservation -> scatter ---------------
// cursor[] must be zeroed before launch. binned word = (local_dst[8b]<<18)|src.
__global__ void lgcn_bin(const int* __restrict__ row, const int* __restrict__ col,
                         int* __restrict__ cursor, int* __restrict__ binned, int EH) {
    __shared__ int h[4 * NB];
    __shared__ int basecur[NB];
    for (int i = threadIdx.x; i < 4 * NB; i += blockDim.x) h[i] = 0;
    __syncthreads();
    int k = blockIdx.x;
    int wv = threadIdx.x >> 6;
    int* hw = h + wv * NB;
    int e0 = k * PAIRS_PER_BLK;
    int e1 = min(EH, e0 + PAIRS_PER_BLK);
    int nq = (e1 - e0) >> 2;                     // both multiples of 4
    const int4* r4 = (const int4*)(row + e0);
    const int4* c4 = (const int4*)(col + e0);
    for (int q = threadIdx.x; q < nq; q += blockDim.x) {
        int4 r = r4[q];
        int4 c = c4[q];
        atomicAdd(&hw[r.x >> BSHIFT], 1); atomicAdd(&hw[c.x >> BSHIFT], 1);
        atomicAdd(&hw[r.y >> BSHIFT], 1); atomicAdd(&hw[c.y >> BSHIFT], 1);
        atomicAdd(&hw[r.z >> BSHIFT], 1); atomicAdd(&hw[c.z >> BSHIFT], 1);
        atomicAdd(&hw[r.w >> BSHIFT], 1); atomicAdd(&hw[c.w >> BSHIFT], 1);
    }
    __syncthreads();
    for (int i = threadIdx.x; i < NB; i += blockDim.x) {
        int tot = h[i] + h[NB + i] + h[2 * NB + i] + h[3 * NB + i];
        int base = i << CAPSHIFT;
        if (tot) base += atomicAdd(&cursor[i], tot);   // reserve range
        basecur[i] = base;
    }
    __syncthreads();
    for (int q = threadIdx.x; q < nq; q += blockDim.x) {
        int4 r = r4[q];
        int4 c = c4[q];
        int rr[4] = { r.x, r.y, r.z, r.w };
        int cc[4] = { c.x, c.y, c.z, c.w };
#pragma unroll
        for (int j = 0; j < 4; ++j) {
            int p1 = atomicAdd(&basecur[cc[j] >> BSHIFT], 1);  // LDS atomic
            binned[p1] = ((cc[j] & (BUCKET - 1)) << 18) | rr[j];
            int p2 = atomicAdd(&basecur[rr[j] >> BSHIFT], 1);
            binned[p2] = ((rr[j] & (BUCKET - 1)) << 18) | cc[j];
        }
    }
}

// --- Per-bucket padded CSR -------------------------------------------------
// Node segments padded to multiple of 4; pad slots = N_NODES (zero row).
// nodeinfo = {start, deg, bits(1/sqrt(da)), bits(sqrt(da))}.
__global__ void __launch_bounds__(BUCKET)
lgcn_build_csr(const int* __restrict__ cursor, const int* __restrict__ binned,
               int4* __restrict__ nodeinfo, int* __restrict__ packed) {
    __shared__ int hist[BUCKET], sA[BUCKET], sB[BUCKET], cur[BUCKET];
    int b = blockIdx.x;
    int tid = threadIdx.x;
    hist[tid] = 0;
    __syncthreads();
    int e0 = b << CAPSHIFT;
    int e1 = e0 + cursor[b];                   // bucket edge count
    for (int j = e0 + tid; j < e1; j += BUCKET)
        atomicAdd(&hist[binned[j] >> 18], 1);
    __syncthreads();
    int deg = hist[tid];
    int degp = (deg + 3) & ~3;                 // padded segment length
    sA[tid] = degp;
    __syncthreads();
    int* c_ = sA; int* n_ = sB;
    for (int off = 1; off < BUCKET; off <<= 1) {
        n_[tid] = (tid >= off) ? c_[tid] + c_[tid - off] : c_[tid];
        __syncthreads();
        int* t = c_; c_ = n_; n_ = t;
    }
    int start = e0 + (c_[tid] - degp);         // exclusive scan, int4-aligned
    cur[tid] = start;
    int node = (b << BSHIFT) + tid;
    if (node < N_NODES) {
        float da = (deg == 0) ? 1.0f : (float)deg;
        float sq = sqrtf(da);
        int4 ni;
        ni.x = start;
        ni.y = deg;
        ni.z = __float_as_int(1.0f / sq);
        ni.w = __float_as_int(sq);
        nodeinfo[node] = ni;
    }
    __syncthreads();
    for (int j = e0 + tid; j < e1; j += BUCKET) {
        int w = binned[j];
        int pos = atomicAdd(&cur[w >> 18], 1); // LDS atomic
        packed[pos] = w & 0x3FFFF;             // src only
    }
    // Pad slots -> zero row (disjoint from all scatter targets; no sync needed).
    for (int kk = deg; kk < degp; ++kk)
        packed[start + kk] = N_NODES;
}

// --- Propagation -----------------------------------------------------------

// g0[n] = norm[n] * x[n]  (bf16), plus zero row N_NODES in BOTH buffers.
__global__ void lgcn_init_g0(const float* __restrict__ ue, const float* __restrict__ ie,
                             const int4* __restrict__ nodeinfo,
                             bf16_t* __restrict__ g0, bf16_t* __restrict__ g1) {
    int t = blockIdx.x * blockDim.x + threadIdx.x;     // ushort4-chunk slot
    const int nT = N_NODES * (DIM / 4);
    if (t >= nT) {
        if (t < nT + 16)
            ((ushort4*)g0)[nT + (t - nT)] = make_ushort4(0, 0, 0, 0);
        else if (t < nT + 32)
            ((ushort4*)g1)[nT + (t - nT - 16)] = make_ushort4(0, 0, 0, 0);
        return;
    }
    int n = t >> 4;
    const int nU = N_USERS * (DIM / 4);
    float4 x = (t < nU) ? ((const float4*)ue)[t] : ((const float4*)ie)[t - nU];
    float nm = __int_as_float(nodeinfo[n].z);
    ushort4 o;
    o.x = f2bf(x.x * nm); o.y = f2bf(x.y * nm);
    o.z = f2bf(x.z * nm); o.w = f2bf(x.w * nm);
    ((ushort4*)g0)[t] = o;
}

// Gather core: 16-lane group sums g rows for edges [start, start+deg).
// Pad slots point at the zero row -> plain adds, no clamps, no weights.
static __device__ __forceinline__ float4
gather_sum(const bf16_t* __restrict__ g, const int* __restrict__ packed,
           int start, int deg, int grp, int c) {
    float4 acc = make_float4(0.f, 0.f, 0.f, 0.f);
    for (int o = 4 * grp; o < deg; o += 16) {
        int4 e4 = *(const int4*)(packed + start + o);  // 16-B aligned
        ushort4 v0 = ((const ushort4*)(g + (size_t)e4.x * DIM))[c];
        ushort4 v1 = ((const ushort4*)(g + (size_t)e4.y * DIM))[c];
        ushort4 v2 = ((const ushort4*)(g + (size_t)e4.z * DIM))[c];
        ushort4 v3 = ((const ushort4*)(g + (size_t)e4.w * DIM))[c];
        acc.x += bf2f(v0.x); acc.y += bf2f(v0.y);
        acc.z += bf2f(v0.z); acc.w += bf2f(v0.w);
        acc.x += bf2f(v1.x); acc.y += bf2f(v1.y);
        acc.z += bf2f(v1.z); acc.w += bf2f(v1.w);
        acc.x += bf2f(v2.x); acc.y += bf2f(v2.y);
        acc.z += bf2f(v2.z); acc.w += bf2f(v2.w);
        acc.x += bf2f(v3.x); acc.y += bf2f(v3.y);
        acc.z += bf2f(v3.z); acc.w += bf2f(v3.w);
    }
    return acc;
}

// Full pull: gn[n] = bf16( norm[n]^2 * sum_{s in N(n)} g[s] ).
__global__ void __launch_bounds__(256)
lgcn_pull(const bf16_t* __restrict__ g, const int4* __restrict__ nodeinfo,
          const int* __restrict__ packed, bf16_t* __restrict__ gn) {
    int n = blockIdx.x * 4 + (threadIdx.x >> 6);
    if (n >= N_NODES) return;
    int lane = threadIdx.x & 63;
    int grp = lane >> 4;
    int c = lane & 15;
    int4 ni = nodeinfo[n];
    float4 acc = gather_sum(g, packed, ni.x, ni.y, grp, c);
#pragma unroll
    for (int off = 16; off < 64; off <<= 1) {
        acc.x += __shfl_xor(acc.x, off, 64);
        acc.y += __shfl_xor(acc.y, off, 64);
        acc.z += __shfl_xor(acc.z, off, 64);
        acc.w += __shfl_xor(acc.w, off, 64);
    }
    if (lane < 16) {
        float nm = __int_as_float(ni.z);
        float s2 = nm * nm;
        ushort4 o;
        o.x = f2bf(acc.x * s2); o.y = f2bf(acc.y * s2);
        o.z = f2bf(acc.z * s2); o.w = f2bf(acc.w * s2);
        ((ushort4*)(gn + (size_t)n * DIM))[c] = o;
    }
}

// Fused layer-3 + epilogue, batch nodes only:
// out[slot] = 0.25*( x[n] + rn*g1[n] + rn*g2[n] + nm*sum_{s in N(n)} g2[s] ).
__global__ void __launch_bounds__(256)
lgcn_final(const float* __restrict__ ue, const float* __restrict__ ie,
           const bf16_t* __restrict__ g1, const bf16_t* __restrict__ g2,
           const int4* __restrict__ nodeinfo, const int* __restrict__ packed,
           const int* __restrict__ uid, const int* __restrict__ iid,
           float* __restrict__ out) {
    int slot = blockIdx.x * 4 + (threadIdx.x >> 6);
    if (slot >= 2 * BATCH) return;
    int lane = threadIdx.x & 63;
    int grp = lane >> 4;
    int c = lane & 15;
    int isItem = slot >= BATCH;
    int b = isItem ? (slot - BATCH) : slot;
    int node = isItem ? (N_USERS + iid[b]) : uid[b];
    int4 ni = nodeinfo[node];
    float4 acc = gather_sum(g2, packed, ni.x, ni.y, grp, c);
#pragma unroll
    for (int off = 16; off < 64; off <<= 1) {
        acc.x += __shfl_xor(acc.x, off, 64);
        acc.y += __shfl_xor(acc.y, off, 64);
        acc.z += __shfl_xor(acc.z, off, 64);
        acc.w += __shfl_xor(acc.w, off, 64);
    }
    if (lane < 16) {
        const float* xb = isItem ? (ie + (size_t)(node - N_USERS) * DIM)
                                 : (ue + (size_t)node * DIM);
        float4 x = ((const float4*)xb)[c];
        ushort4 a1 = ((const ushort4*)(g1 + (size_t)node * DIM))[c];
        ushort4 a2 = ((const ushort4*)(g2 + (size_t)node * DIM))[c];
        float rn = __int_as_float(ni.w);
        float nm = __int_as_float(ni.z);
        float4 r;
        r.x = 0.25f * (x.x + rn * (bf2f(a1.x) + bf2f(a2.x)) + nm * acc.x);
        r.y = 0.25f * (x.y + rn * (bf2f(a1.y) + bf2f(a2.y)) + nm * acc.y);
        r.z = 0.25f * (x.z + rn * (bf2f(a1.z) + bf2f(a2.z)) + nm * acc.z);
        r.w = 0.25f * (x.w + rn * (bf2f(a1.w) + bf2f(a2.w)) + nm * acc.w);
        ((float4*)(out + (size_t)slot * DIM))[c] = r;
    }
}

// --- Launch ----------------------------------------------------------------

extern "C" void kernel_launch(void* const* d_in, const int* in_sizes, int n_in,
                              void* d_out, int out_size, void* d_ws, size_t ws_size,
                              hipStream_t stream) {
    const float* ue  = (const float*)d_in[0];
    const float* ie  = (const float*)d_in[1];
    const int*   ei  = (const int*)d_in[3];
    const int*   uid = (const int*)d_in[4];
    const int*   iid = (const int*)d_in[5];
    float* out = (float*)d_out;

    const int E  = in_sizes[2];     // 2,000,000 directed edges
    const int EH = E / 2;           // 1,000,000 undirected pairs
    const int* row = ei;            // first-half src = user ids
    const int* col = ei + E;        // first-half dst = item node ids

    const int NB1 = (EH + PAIRS_PER_BLK - 1) / PAIRS_PER_BLK;   // 489

    // Workspace carve-up (256-B aligned), ~80 MB total.
    char* p = (char*)d_ws;
    size_t off = 0;
    auto carve = [&](size_t bytes) -> char* {
        char* r = p + off;
        off += (bytes + 255) & ~(size_t)255;
        return r;
    };
    const size_t nodeBf16 = (size_t)(N_NODES + 1) * DIM * sizeof(bf16_t); // +zero row
    bf16_t* gA       = (bf16_t*)carve(nodeBf16);
    bf16_t* gB       = (bf16_t*)carve(nodeBf16);
    int4*   nodeinfo = (int4*)carve((size_t)N_NODES * sizeof(int4));     // 2.4 MB
    int*    cursor   = (int*)carve((size_t)NB * sizeof(int));
    int*    binned   = (int*)carve((size_t)NB * CAP * sizeof(int));      // 19.2 MB
    int*    packed   = (int*)carve((size_t)NB * CAP * sizeof(int));      // 19.2 MB
    (void)ws_size;

    // 1) Binning (cursor must start at zero) + per-bucket CSR.
    hipMemsetAsync(cursor, 0, (size_t)NB * sizeof(int), stream);
    lgcn_bin<<<NB1, 256, 0, stream>>>(row, col, cursor, binned, EH);
    lgcn_build_csr<<<NB, BUCKET, 0, stream>>>(cursor, binned, nodeinfo, packed);

    // 2) g0 = norm*x (bf16) + zero rows in both buffers.
    lgcn_init_g0<<<(N_NODES * (DIM / 4) + 32 + 255) / 256, 256, 0, stream>>>(
        ue, ie, nodeinfo, gA, gB);

    // 3) Two full pulls (g1, g2), then fused batch-only layer 3 + epilogue.
    const int pullGrid = (N_NODES + 3) / 4;
    lgcn_pull<<<pullGrid, 256, 0, stream>>>(gA, nodeinfo, packed, gB);  // g1 = gB
    lgcn_pull<<<pullGrid, 256, 0, stream>>>(gB, nodeinfo, packed, gA);  // g2 = gA
    lgcn_final<<<(2 * BATCH + 3) / 4, 256, 0, stream>>>(
        ue, ie, gB, gA, nodeinfo, packed, uid, iid, out);
}

// Round 3
// 229.962 us; speedup vs baseline: 1.9028x; 1.0675x over previous
//
#include <hip/hip_runtime.h>

// LightGCN encoder on MI355X — round 10.
// Rounds 8/9 post-mortem: scattered 4 B global stores into regions shared by
// many blocks across 8 non-coherent XCD L2s cause partial-line write
// amplification (round 8 counters: WRITE_SIZE 128 MB for an 8 MB scatter).
// Round 10 makes EVERY global write coalesced:
//   - lgcn_bin: block-exclusive strip counting-sort in LDS (hist -> scan ->
//     LDS scatter), then int4-coalesced 16 KB strip write + per-strip bucket
//     offset table pos[strip][NB+1]. No global cursor, no memset, no atomics.
//   - lgcn_build_csr: gathers bucket b's runs from all strips (short
//     scattered READS — reads don't write-amplify), stages in LDS, per-node
//     hist/scan, scatters into a second LDS buffer (pads prefilled with the
//     zero row), writes the bucket region with coalesced int4 stores.
// Propagation kernels (init_g0 / pull / final) byte-identical to rounds 7-9.
#define N_USERS 100000
#define N_NODES 150000
#define DIM 64
#define BATCH 4096
#define BSHIFT 8
#define BUCKET 256
#define NB 586                 // ceil(150000 / 256) buckets
#define NBP 768                // padded bucket count for the 3-per-thread scan
#define PAIRS_PER_BLK 2048     // undirected pairs per binning block
#define STRIP 4096             // directed edges (words) per strip
#define CAPSHIFT 13
#define CAP (1 << CAPSHIFT)    // packed slots per bucket (max ~6.3K used)

typedef unsigned short bf16_t;

static __device__ __forceinline__ float bf2f(bf16_t h) {
    return __uint_as_float(((unsigned)h) << 16);
}
static __device__ __forceinline__ bf16_t f2bf(float f) {  // round-nearest-even
    unsigned u = __float_as_uint(f);
    return (bf16_t)((u + 0x7FFFu + ((u >> 16) & 1u)) >> 16);
}

// --- Strip sort: LDS counting-sort of 4096 directed edges by bucket --------
// binned word = (local_dst[8b]<<18)|src. pos[k*(NB+1)+b] = run start of
// bucket b in strip k; pos[k*(NB+1)+NB] = edge count of strip k.
__global__ void __launch_bounds__(256)
lgcn_bin(const int* __restrict__ row, const int* __restrict__ col,
         int* __restrict__ pos, int* __restrict__ binned, int EH) {
    __shared__ int cnt[NBP];
    __shared__ int sA[256], sB[256];
    __shared__ int base[NB + 2];
    __shared__ int stage[STRIP];
    int tid = threadIdx.x;
    int k = blockIdx.x;
    cnt[tid] = 0; cnt[tid + 256] = 0; cnt[tid + 512] = 0;
    __syncthreads();
    int e0 = k * PAIRS_PER_BLK;
    int e1 = min(EH, e0 + PAIRS_PER_BLK);
    int n = e1 - e0;                           // pairs (multiple of 4)
    int nq = n >> 2;
    const int4* r4 = (const int4*)(row + e0);
    const int4* c4 = (const int4*)(col + e0);
    for (int q = tid; q < nq; q += 256) {
        int4 r = r4[q]; int4 c = c4[q];
        atomicAdd(&cnt[r.x >> BSHIFT], 1); atomicAdd(&cnt[c.x >> BSHIFT], 1);
        atomicAdd(&cnt[r.y >> BSHIFT], 1); atomicAdd(&cnt[c.y >> BSHIFT], 1);
        atomicAdd(&cnt[r.z >> BSHIFT], 1); atomicAdd(&cnt[c.z >> BSHIFT], 1);
        atomicAdd(&cnt[r.w >> BSHIFT], 1); atomicAdd(&cnt[c.w >> BSHIFT], 1);
    }
    __syncthreads();
    // Exclusive scan over NBP buckets, 3 per thread (stride-3 -> bank-clean).
    int c0 = cnt[3 * tid], c1 = cnt[3 * tid + 1], c2 = cnt[3 * tid + 2];
    int s = c0 + c1 + c2;
    sA[tid] = s;
    __syncthreads();
    int* c_ = sA; int* n_ = sB;
    for (int off = 1; off < 256; off <<= 1) {
        n_[tid] = (tid >= off) ? c_[tid] + c_[tid - off] : c_[tid];
        __syncthreads();
        int* t = c_; c_ = n_; n_ = t;
    }
    int excl = c_[tid] - s;
    if (3 * tid     <= NB) base[3 * tid]     = excl;
    if (3 * tid + 1 <= NB) base[3 * tid + 1] = excl + c0;
    if (3 * tid + 2 <= NB) base[3 * tid + 2] = excl + c0 + c1;
    __syncthreads();
    // pos table (coalesced) + LDS cursors (reuse cnt).
    for (int i = tid; i <= NB; i += 256) {
        pos[k * (NB + 1) + i] = base[i];
        cnt[i] = base[i];
    }
    __syncthreads();
    // LDS scatter (re-read pairs; 16 KB/block -> L2-hot).
    for (int q = tid; q < nq; q += 256) {
        int4 r = r4[q]; int4 c = c4[q];
        int rr[4] = { r.x, r.y, r.z, r.w };
        int cc[4] = { c.x, c.y, c.z, c.w };
#pragma unroll
        for (int j = 0; j < 4; ++j) {
            int p1 = atomicAdd(&cnt[cc[j] >> BSHIFT], 1);
            stage[p1] = ((cc[j] & (BUCKET - 1)) << 18) | rr[j];
            int p2 = atomicAdd(&cnt[rr[j] >> BSHIFT], 1);
            stage[p2] = ((rr[j] & (BUCKET - 1)) << 18) | cc[j];
        }
    }
    __syncthreads();
    // Coalesced strip write-out.
    int m4 = (2 * n) >> 2;
    int4* dst = (int4*)(binned + k * STRIP);
    const int4* st4 = (const int4*)stage;
    for (int j = tid; j < m4; j += 256) dst[j] = st4[j];
}

// --- Per-bucket padded CSR (gather strips -> LDS sort -> coalesced write) --
// Node segments padded to multiple of 4; pad slots = N_NODES (zero row).
// nodeinfo = {start, deg, bits(1/sqrt(da)), bits(sqrt(da))}.
__global__ void __launch_bounds__(256)
lgcn_build_csr(const int* __restrict__ pos, const int* __restrict__ binned,
               int4* __restrict__ nodeinfo, int* __restrict__ packed, int nblk) {
    __shared__ int stage[CAP];     // gathered edges of this bucket
    __shared__ int sorted[CAP];    // node-sorted + padded
    __shared__ int sA[256], sB[256];
    __shared__ int hist[256], cur[256];
    int b = blockIdx.x;
    int tid = threadIdx.x;
    // Runs for strips tid and tid+256.
    int a0 = 0, l0 = 0, a1 = 0, l1 = 0;
    if (tid < nblk) {
        const int* pk = pos + tid * (NB + 1) + b;
        a0 = pk[0]; l0 = pk[1] - a0;
    }
    if (tid + 256 < nblk) {
        const int* pk = pos + (tid + 256) * (NB + 1) + b;
        a1 = pk[0]; l1 = pk[1] - a1;
    }
    int u = l0 + l1;
    sA[tid] = u;
    __syncthreads();
    int* c_ = sA; int* n_ = sB;
    for (int off = 1; off < 256; off <<= 1) {
        n_[tid] = (tid >= off) ? c_[tid] + c_[tid - off] : c_[tid];
        __syncthreads();
        int* t = c_; c_ = n_; n_ = t;
    }
    int myBase = c_[tid] - u;
    int Eb = c_[255];
    __syncthreads();
    // Gather runs into stage (short scattered reads).
    {
        const int* s0 = binned + tid * STRIP + a0;
        for (int i = 0; i < l0; ++i) stage[myBase + i] = s0[i];
        const int* s1 = binned + (tid + 256) * STRIP + a1;
        for (int i = 0; i < l1; ++i) stage[myBase + l0 + i] = s1[i];
    }
    hist[tid] = 0;
    __syncthreads();
    for (int j = tid; j < Eb; j += 256)
        atomicAdd(&hist[stage[j] >> 18], 1);
    __syncthreads();
    int deg = hist[tid];
    int degp = (deg + 3) & ~3;               // padded segment length
    sA[tid] = degp;
    __syncthreads();
    int* c2 = sA; int* n2 = sB;
    for (int off = 1; off < 256; off <<= 1) {
        n2[tid] = (tid >= off) ? c2[tid] + c2[tid - off] : c2[tid];
        __syncthreads();
        int* t = c2; c2 = n2; n2 = t;
    }
    int startLoc = c2[tid] - degp;           // local, int4-aligned
    int totPad = c2[255];
    cur[tid] = startLoc;
    int gstart = (b << CAPSHIFT) + startLoc;
    int node = (b << BSHIFT) + tid;
    if (node < N_NODES) {
        float da = (deg == 0) ? 1.0f : (float)deg;
        float sq = sqrtf(da);
        int4 ni;
        ni.x = gstart;
        ni.y = deg;
        ni.z = __float_as_int(1.0f / sq);
        ni.w = __float_as_int(sq);
        nodeinfo[node] = ni;
    }
    // Prefill (covers pad slots with the zero row).
    for (int j = tid; j < totPad; j += 256) sorted[j] = N_NODES;
    __syncthreads();
    for (int j = tid; j < Eb; j += 256) {
        int w = stage[j];
        int p = atomicAdd(&cur[w >> 18], 1);  // LDS atomic
        sorted[p] = w & 0x3FFFF;
    }
    __syncthreads();
    // Coalesced bucket-region write-out.
    int4* dst = (int4*)(packed + (b << CAPSHIFT));
    const int4* s4 = (const int4*)sorted;
    for (int j = tid; j < (totPad >> 2); j += 256) dst[j] = s4[j];
}

// --- Propagation -----------------------------------------------------------

// g0[n] = norm[n] * x[n]  (bf16), plus zero row N_NODES in BOTH buffers.
__global__ void lgcn_init_g0(const float* __restrict__ ue, const float* __restrict__ ie,
                             const int4* __restrict__ nodeinfo,
                             bf16_t* __restrict__ g0, bf16_t* __restrict__ g1) {
    int t = blockIdx.x * blockDim.x + threadIdx.x;     // ushort4-chunk slot
    const int nT = N_NODES * (DIM / 4);
    if (t >= nT) {
        if (t < nT + 16)
            ((ushort4*)g0)[nT + (t - nT)] = make_ushort4(0, 0, 0, 0);
        else if (t < nT + 32)
            ((ushort4*)g1)[nT + (t - nT - 16)] = make_ushort4(0, 0, 0, 0);
        return;
    }
    int n = t >> 4;
    const int nU = N_USERS * (DIM / 4);
    float4 x = (t < nU) ? ((const float4*)ue)[t] : ((const float4*)ie)[t - nU];
    float nm = __int_as_float(nodeinfo[n].z);
    ushort4 o;
    o.x = f2bf(x.x * nm); o.y = f2bf(x.y * nm);
    o.z = f2bf(x.z * nm); o.w = f2bf(x.w * nm);
    ((ushort4*)g0)[t] = o;
}

// Gather core: 16-lane group sums g rows for edges [start, start+deg).
// Pad slots point at the zero row -> plain adds, no clamps, no weights.
static __device__ __forceinline__ float4
gather_sum(const bf16_t* __restrict__ g, const int* __restrict__ packed,
           int start, int deg, int grp, int c) {
    float4 acc = make_float4(0.f, 0.f, 0.f, 0.f);
    for (int o = 4 * grp; o < deg; o += 16) {
        int4 e4 = *(const int4*)(packed + start + o);  // 16-B aligned
        ushort4 v0 = ((const ushort4*)(g + (size_t)e4.x * DIM))[c];
        ushort4 v1 = ((const ushort4*)(g + (size_t)e4.y * DIM))[c];
        ushort4 v2 = ((const ushort4*)(g + (size_t)e4.z * DIM))[c];
        ushort4 v3 = ((const ushort4*)(g + (size_t)e4.w * DIM))[c];
        acc.x += bf2f(v0.x); acc.y += bf2f(v0.y);
        acc.z += bf2f(v0.z); acc.w += bf2f(v0.w);
        acc.x += bf2f(v1.x); acc.y += bf2f(v1.y);
        acc.z += bf2f(v1.z); acc.w += bf2f(v1.w);
        acc.x += bf2f(v2.x); acc.y += bf2f(v2.y);
        acc.z += bf2f(v2.z); acc.w += bf2f(v2.w);
        acc.x += bf2f(v3.x); acc.y += bf2f(v3.y);
        acc.z += bf2f(v3.z); acc.w += bf2f(v3.w);
    }
    return acc;
}

// Full pull: gn[n] = bf16( norm[n]^2 * sum_{s in N(n)} g[s] ).
__global__ void __launch_bounds__(256)
lgcn_pull(const bf16_t* __restrict__ g, const int4* __restrict__ nodeinfo,
          const int* __restrict__ packed, bf16_t* __restrict__ gn) {
    int n = blockIdx.x * 4 + (threadIdx.x >> 6);
    if (n >= N_NODES) return;
    int lane = threadIdx.x & 63;
    int grp = lane >> 4;
    int c = lane & 15;
    int4 ni = nodeinfo[n];
    float4 acc = gather_sum(g, packed, ni.x, ni.y, grp, c);
#pragma unroll
    for (int off = 16; off < 64; off <<= 1) {
        acc.x += __shfl_xor(acc.x, off, 64);
        acc.y += __shfl_xor(acc.y, off, 64);
        acc.z += __shfl_xor(acc.z, off, 64);
        acc.w += __shfl_xor(acc.w, off, 64);
    }
    if (lane < 16) {
        float nm = __int_as_float(ni.z);
        float s2 = nm * nm;
        ushort4 o;
        o.x = f2bf(acc.x * s2); o.y = f2bf(acc.y * s2);
        o.z = f2bf(acc.z * s2); o.w = f2bf(acc.w * s2);
        ((ushort4*)(gn + (size_t)n * DIM))[c] = o;
    }
}

// Fused layer-3 + epilogue, batch nodes only:
// out[slot] = 0.25*( x[n] + rn*g1[n] + rn*g2[n] + nm*sum_{s in N(n)} g2[s] ).
__global__ void __launch_bounds__(256)
lgcn_final(const float* __restrict__ ue, const float* __restrict__ ie,
           const bf16_t* __restrict__ g1, const bf16_t* __restrict__ g2,
           const int4* __restrict__ nodeinfo, const int* __restrict__ packed,
           const int* __restrict__ uid, const int* __restrict__ iid,
           float* __restrict__ out) {
    int slot = blockIdx.x * 4 + (threadIdx.x >> 6);
    if (slot >= 2 * BATCH) return;
    int lane = threadIdx.x & 63;
    int grp = lane >> 4;
    int c = lane & 15;
    int isItem = slot >= BATCH;
    int b = isItem ? (slot - BATCH) : slot;
    int node = isItem ? (N_USERS + iid[b]) : uid[b];
    int4 ni = nodeinfo[node];
    float4 acc = gather_sum(g2, packed, ni.x, ni.y, grp, c);
#pragma unroll
    for (int off = 16; off < 64; off <<= 1) {
        acc.x += __shfl_xor(acc.x, off, 64);
        acc.y += __shfl_xor(acc.y, off, 64);
        acc.z += __shfl_xor(acc.z, off, 64);
        acc.w += __shfl_xor(acc.w, off, 64);
    }
    if (lane < 16) {
        const float* xb = isItem ? (ie + (size_t)(node - N_USERS) * DIM)
                                 : (ue + (size_t)node * DIM);
        float4 x = ((const float4*)xb)[c];
        ushort4 a1 = ((const ushort4*)(g1 + (size_t)node * DIM))[c];
        ushort4 a2 = ((const ushort4*)(g2 + (size_t)node * DIM))[c];
        float rn = __int_as_float(ni.w);
        float nm = __int_as_float(ni.z);
        float4 r;
        r.x = 0.25f * (x.x + rn * (bf2f(a1.x) + bf2f(a2.x)) + nm * acc.x);
        r.y = 0.25f * (x.y + rn * (bf2f(a1.y) + bf2f(a2.y)) + nm * acc.y);
        r.z = 0.25f * (x.z + rn * (bf2f(a1.z) + bf2f(a2.z)) + nm * acc.z);
        r.w = 0.25f * (x.w + rn * (bf2f(a1.w) + bf2f(a2.w)) + nm * acc.w);
        ((float4*)(out + (size_t)slot * DIM))[c] = r;
    }
}

// --- Launch ----------------------------------------------------------------

extern "C" void kernel_launch(void* const* d_in, const int* in_sizes, int n_in,
                              void* d_out, int out_size, void* d_ws, size_t ws_size,
                              hipStream_t stream) {
    const float* ue  = (const float*)d_in[0];
    const float* ie  = (const float*)d_in[1];
    const int*   ei  = (const int*)d_in[3];
    const int*   uid = (const int*)d_in[4];
    const int*   iid = (const int*)d_in[5];
    float* out = (float*)d_out;

    const int E  = in_sizes[2];     // 2,000,000 directed edges
    const int EH = E / 2;           // 1,000,000 undirected pairs
    const int* row = ei;            // first-half src = user ids
    const int* col = ei + E;        // first-half dst = item node ids

    const int nblk = (EH + PAIRS_PER_BLK - 1) / PAIRS_PER_BLK;   // 489

    // Workspace carve-up (256-B aligned), ~70 MB total.
    char* p = (char*)d_ws;
    size_t off = 0;
    auto carve = [&](size_t bytes) -> char* {
        char* r = p + off;
        off += (bytes + 255) & ~(size_t)255;
        return r;
    };
    const size_t nodeBf16 = (size_t)(N_NODES + 1) * DIM * sizeof(bf16_t); // +zero row
    bf16_t* gA       = (bf16_t*)carve(nodeBf16);
    bf16_t* gB       = (bf16_t*)carve(nodeBf16);
    int4*   nodeinfo = (int4*)carve((size_t)N_NODES * sizeof(int4));       // 2.4 MB
    int*    pos      = (int*)carve((size_t)nblk * (NB + 1) * sizeof(int)); // 1.15 MB
    int*    binned   = (int*)carve((size_t)nblk * STRIP * sizeof(int));    // 8 MB
    int*    packed   = (int*)carve((size_t)NB * CAP * sizeof(int));        // 19.2 MB
    (void)ws_size;

    // 1) Strip sort + per-bucket CSR. All global writes coalesced.
    lgcn_bin<<<nblk, 256, 0, stream>>>(row, col, pos, binned, EH);
    lgcn_build_csr<<<NB, 256, 0, stream>>>(pos, binned, nodeinfo, packed, nblk);

    // 2) g0 = norm*x (bf16) + zero rows in both buffers.
    lgcn_init_g0<<<(N_NODES * (DIM / 4) + 32 + 255) / 256, 256, 0, stream>>>(
        ue, ie, nodeinfo, gA, gB);

    // 3) Two full pulls (g1, g2), then fused batch-only layer 3 + epilogue.
    const int pullGrid = (N_NODES + 3) / 4;
    lgcn_pull<<<pullGrid, 256, 0, stream>>>(gA, nodeinfo, packed, gB);  // g1 = gB
    lgcn_pull<<<pullGrid, 256, 0, stream>>>(gB, nodeinfo, packed, gA);  // g2 = gA
    lgcn_final<<<(2 * BATCH + 3) / 4, 256, 0, stream>>>(
        ue, ie, gB, gA, nodeinfo, packed, uid, iid, out);
}